// Round 19
// baseline (85.784 us; speedup 1.0000x reference)
//
#include <hip/hip_runtime.h>
#include <hip/hip_fp16.h>

typedef unsigned long long ull;
typedef unsigned short ushort_t;
typedef unsigned int u32;
typedef short bf16x8 __attribute__((ext_vector_type(8)));
typedef _Float16 f16x8 __attribute__((ext_vector_type(8)));
typedef float f32x4 __attribute__((ext_vector_type(4)));

#define NC 10000   // H*W cells
#define D_ 256     // input dim
#define B_ 1024    // batch
#define W_ 100     // grid width
#define NTC 157    // scores c-tiles (64 cells each)
#define PTS 160    // pktile row stride (ull)
#define LD 10240   // padded row stride for h
#define FIXMARGIN 0.06f  // >= 2*eps_score(fp16 mfma scores) — proven R5/R13
#define SHORTCAP 128

// async global->LDS, 16B per lane; LDS dest = wave-uniform base + lane*16
__device__ __forceinline__ void gl_lds16(const void* g, void* l) {
    __builtin_amdgcn_global_load_lds(
        (const __attribute__((address_space(1))) u32*)g,
        (__attribute__((address_space(3))) u32*)l,
        16, 0, 0);
}

// bijective XCD-chunk swizzle (m204)
__device__ __forceinline__ int xcd_swz(int orig, int nwg) {
    int q = nwg >> 3, r = nwg & 7;
    int xcd = orig & 7, off = orig >> 3;
    return (xcd < r ? xcd * (q + 1) : r * (q + 1) + (xcd - r) * q) + off;
}

// monotonic float -> sortable uint mapping
__device__ __forceinline__ unsigned fkey(float f) {
    unsigned u = __float_as_uint(f);
    return (u & 0x80000000u) ? ~u : (u | 0x80000000u);
}
__device__ __forceinline__ float unfkey(unsigned k) {
    unsigned u = (k & 0x80000000u) ? (k ^ 0x80000000u) : ~k;
    return __uint_as_float(u);
}

// exact RNE float -> bf16 bits
__device__ __forceinline__ ushort_t f2bf(float f) {
    unsigned u = __float_as_uint(f);
    unsigned r = (u + 0x7fffu + ((u >> 16) & 1u)) >> 16;
    return (ushort_t)r;
}

__device__ __forceinline__ void decay_params(const int* ep, const int* tp, float& lr, float& inv2r2) {
    double decay = 1.0 - (double)(*ep) / (double)(*tp);
    lr = (float)(0.5 * decay);
    float radius = (float)(50.0 * decay);
    inv2r2 = 1.0f / (2.0f * radius * radius);
}

// fused prep: [0,2500) w -> wh+wnorm; [2500,2564) x -> xh+xhT; 2564 = pk1/wnorm-pad init;
// [2565,2605) = pktile init (~0ull)
__global__ __launch_bounds__(256) void k_prep(const float* __restrict__ w, const float* __restrict__ x,
                                              __half* __restrict__ wh, float* __restrict__ wnorm,
                                              __half* __restrict__ xh, ushort_t* __restrict__ xhT,
                                              ull* __restrict__ pk1, ull* __restrict__ pktile) {
    int bid = blockIdx.x;
    int tid = threadIdx.x;
    if (bid < NC / 4) {
        int cell = bid * 4 + (tid >> 6);
        int lane = tid & 63;
        float4 v = *reinterpret_cast<const float4*>(&w[(size_t)cell * D_ + lane * 4]);
        float s = v.x * v.x + v.y * v.y + v.z * v.z + v.w * v.w;
        __half hb[4];
        float e[4] = {v.x, v.y, v.z, v.w};
        #pragma unroll
        for (int i = 0; i < 4; ++i) hb[i] = __float2half(e[i]);
        *reinterpret_cast<uint2*>(&wh[(size_t)cell * D_ + lane * 4]) = *reinterpret_cast<uint2*>(hb);
        #pragma unroll
        for (int off = 32; off; off >>= 1) s += __shfl_xor(s, off);
        if (lane == 0) wnorm[cell] = s;
    } else if (bid < NC / 4 + 64) {
        __shared__ ushort_t tile[64][65];
        int idx = bid - NC / 4;
        int b0 = (idx & 15) * 64, d0 = (idx >> 4) * 64;
        #pragma unroll
        for (int r = 0; r < 16; ++r) {
            int f = r * 256 + tid;
            int i = f >> 6, j = f & 63;       // i = b-local, j = d-local
            float v = x[(size_t)(b0 + i) * D_ + d0 + j];
            xh[(size_t)(b0 + i) * D_ + d0 + j] = __float2half(v);
            tile[j][i] = f2bf(v);
        }
        __syncthreads();
        #pragma unroll
        for (int r = 0; r < 2; ++r) {
            int f = r * 256 + tid;            // [0,512): 64 d-rows x 8 units
            int row = f >> 3, u = f & 7;
            ushort_t v[8];
            #pragma unroll
            for (int e = 0; e < 8; ++e) v[e] = tile[row][u * 8 + e];
            *reinterpret_cast<uint4*>(&xhT[(size_t)(d0 + row) * B_ + b0 + u * 8]) =
                *reinterpret_cast<uint4*>(v);
        }
    } else if (bid == NC / 4 + 64) {
        #pragma unroll
        for (int k = 0; k < 4; ++k) pk1[tid * 4 + k] = ~0ull;
        if (tid < 128) wnorm[NC + tid] = __builtin_inff();
    } else {
        size_t base = (size_t)(bid - (NC / 4 + 65)) * 4096 + (size_t)tid * 16;  // 40 blocks x 4096
        #pragma unroll
        for (int k = 0; k < 16; ++k) pktile[base + k] = ~0ull;                  // covers B_*PTS
    }
}

// fp16 scores GEMM: tile 64 cells x 128 batch, BK=64, 8 waves — 2-phase issue-early staging;
// fused epilogue: per-sample min1 -> pk1 atomic AND per-tile min -> pktile atomic
__global__ __launch_bounds__(512) void k_scores_mfma(const __half* __restrict__ wh, const __half* __restrict__ xh,
                                                     const float* __restrict__ wnorm, __half* __restrict__ h,
                                                     ull* __restrict__ pk1, ull* __restrict__ pktile) {
    __shared__ __align__(16) __half As[2][64 * 64];    // 2 x 8KB
    __shared__ __align__(16) __half Bs[2][128 * 64];   // 2 x 16KB
    const int tid = threadIdx.x;
    int orig = blockIdx.y * gridDim.x + blockIdx.x;
    int wgid = xcd_swz(orig, 8 * NTC);
    const int b0 = (wgid & 7) * 128;
    const int c0 = (wgid >> 3) * 64;
    const int tile = wgid >> 3;
    const int wid = tid >> 6, lane = tid & 63;
    const int wc = wid >> 2;           // 0..1 -> 32-cell half
    const int wb = wid & 3;            // 0..3 -> 32-batch quarter
    const int g4 = lane >> 4, l16 = lane & 15;

    f32x4 acc[2][2] = {};

    auto STAGE = [&](int buf, int k0) {
        {   // A: 64 rows x 8 units = 512 (one shot)
            int row = tid >> 3, u = tid & 7;
            int ug = (u ^ (row & 7)) * 8;
            int cc = c0 + row; if (cc > NC - 1) cc = NC - 1;
            gl_lds16(&wh[(size_t)cc * D_ + k0 + ug], &As[buf][(tid & ~63) * 8]);
        }
        #pragma unroll
        for (int r = 0; r < 2; ++r) {   // B: 128 rows x 8 units = 1024
            int f = tid + r * 512;
            int row = f >> 3, u = f & 7;
            int ug = (u ^ (row & 7)) * 8;
            gl_lds16(&xh[(size_t)(b0 + row) * D_ + k0 + ug], &Bs[buf][(f & ~63) * 8]);
        }
    };

    STAGE(0, 0);
    __syncthreads();
    for (int kt = 0; kt < 4; ++kt) {
        int cur = kt & 1;
        if (kt < 3) STAGE(cur ^ 1, (kt + 1) * 64);
        #pragma unroll
        for (int kh = 0; kh < 2; ++kh) {
            int ubase = kh * 4 + g4;
            f16x8 bfr[2];
            #pragma unroll
            for (int fn = 0; fn < 2; ++fn) {
                int rowb = wb * 32 + fn * 16 + l16;
                bfr[fn] = *reinterpret_cast<const f16x8*>(&Bs[cur][rowb * 64 + ((ubase ^ (rowb & 7)) * 8)]);
            }
            #pragma unroll
            for (int fm = 0; fm < 2; ++fm) {
                int rowa = wc * 32 + fm * 16 + l16;
                f16x8 af = *reinterpret_cast<const f16x8*>(&As[cur][rowa * 64 + ((ubase ^ (rowa & 7)) * 8)]);
                #pragma unroll
                for (int fn = 0; fn < 2; ++fn)
                    acc[fm][fn] = __builtin_amdgcn_mfma_f32_16x16x32_f16(af, bfr[fn], acc[fm][fn], 0, 0, 0);
            }
        }
        __syncthreads();
    }

    // store h (dot, fp16)
    #pragma unroll
    for (int fm = 0; fm < 2; ++fm) {
        int cb = c0 + wc * 32 + fm * 16 + g4 * 4;
        #pragma unroll
        for (int fn = 0; fn < 2; ++fn) {
            int b = b0 + wb * 32 + fn * 16 + l16;
            __half hv[4];
            #pragma unroll
            for (int r = 0; r < 4; ++r) hv[r] = __float2half(acc[fm][fn][r]);
            *reinterpret_cast<uint2*>(&h[(size_t)b * LD + cb]) = *reinterpret_cast<uint2*>(hv);
        }
    }

    // fused min1 + per-tile min (wnorm pad = +inf covers phantom cells)
    ull best[2] = {~0ull, ~0ull};
    #pragma unroll
    for (int fm = 0; fm < 2; ++fm) {
        int cb = c0 + wc * 32 + fm * 16 + g4 * 4;
        float4 wn4 = *reinterpret_cast<const float4*>(&wnorm[cb]);
        float wna[4] = {wn4.x, wn4.y, wn4.z, wn4.w};
        #pragma unroll
        for (int fn = 0; fn < 2; ++fn)
            #pragma unroll
            for (int r = 0; r < 4; ++r) {
                float s = wna[r] - 2.0f * acc[fm][fn][r];
                ull p = ((ull)fkey(s) << 32) | (unsigned)(cb + r);
                if (p < best[fn]) best[fn] = p;
            }
    }
    #pragma unroll
    for (int fn = 0; fn < 2; ++fn) {
        ull o = __shfl_xor(best[fn], 16); best[fn] = o < best[fn] ? o : best[fn];
        o = __shfl_xor(best[fn], 32);     best[fn] = o < best[fn] ? o : best[fn];
    }
    if (g4 == 0) {
        int col0 = b0 + wb * 32 + l16, col1 = col0 + 16;
        atomicMin(&pk1[col0], best[0]);
        atomicMin(&pk1[col1], best[1]);
        atomicMin(&pktile[(size_t)col0 * PTS + tile], best[0]);
        atomicMin(&pktile[(size_t)col1 * PTS + tile], best[1]);
    }
}

// two-level fix: candidate tiles from pktile (tilemin <= pk1 + FIXMARGIN), then
// h-shortlist within those tiles only, then exact fp32 dots (R13-proven path)
__global__ __launch_bounds__(256) void k_fix(const __half* __restrict__ h, const float* __restrict__ wnorm,
                                             const float* __restrict__ x, const float* __restrict__ w,
                                             const ull* __restrict__ pk1, const ull* __restrict__ pktile,
                                             int2* __restrict__ bxy) {
    __shared__ int cnt, ctn;
    __shared__ int candT[NTC];
    __shared__ int cand[SHORTCAP];
    __shared__ ull sbest[4];
    int b = blockIdx.x, tid = threadIdx.x;
    if (tid == 0) { cnt = 0; ctn = 0; }
    __syncthreads();
    float thr = unfkey((unsigned)(pk1[b] >> 32)) + FIXMARGIN;
    // level 1: candidate tiles (order-independent final min -> deterministic)
    if (tid < NTC) {
        float tm = unfkey((unsigned)(pktile[(size_t)b * PTS + tid] >> 32));
        if (tm <= thr) {
            int p = atomicAdd(&ctn, 1);
            candT[p] = tid;
        }
    }
    __syncthreads();
    int nt = ctn;
    // level 2: cell shortlist from h, candidate tiles only
    for (int i = tid; i < nt * 64; i += 256) {
        int t = candT[i >> 6];
        int c = t * 64 + (i & 63);
        if (c < NC) {
            float s = wnorm[c] - 2.0f * (float)h[(size_t)b * LD + c];
            if (s <= thr) {
                int p = atomicAdd(&cnt, 1);
                if (p < SHORTCAP) cand[p] = c;
            }
        }
    }
    __syncthreads();
    int n = cnt;
    int wid = tid >> 6, lane = tid & 63;
    float4 xv = *reinterpret_cast<const float4*>(&x[(size_t)b * D_ + lane * 4]);
    ull best = ~0ull;
    if (n <= SHORTCAP) {
        for (int i = wid; i < n; i += 4) {
            int c = cand[i];
            float4 wv = *reinterpret_cast<const float4*>(&w[(size_t)c * D_ + lane * 4]);
            float p = wv.x * (wv.x - 2.0f * xv.x) + wv.y * (wv.y - 2.0f * xv.y)
                    + wv.z * (wv.z - 2.0f * xv.z) + wv.w * (wv.w - 2.0f * xv.w);
            #pragma unroll
            for (int off = 32; off; off >>= 1) p += __shfl_xor(p, off);
            if (lane == 0) {
                ull pk = ((ull)fkey(p) << 32) | (unsigned)c;
                best = pk < best ? pk : best;
            }
        }
    } else {  // pathological overflow: full exact scan (deterministic, ~never taken)
        for (int c = wid; c < NC; c += 4) {
            float4 wv = *reinterpret_cast<const float4*>(&w[(size_t)c * D_ + lane * 4]);
            float p = wv.x * (wv.x - 2.0f * xv.x) + wv.y * (wv.y - 2.0f * xv.y)
                    + wv.z * (wv.z - 2.0f * xv.z) + wv.w * (wv.w - 2.0f * xv.w);
            #pragma unroll
            for (int off = 32; off; off >>= 1) p += __shfl_xor(p, off);
            if (lane == 0) {
                ull pk = ((ull)fkey(p) << 32) | (unsigned)c;
                best = pk < best ? pk : best;
            }
        }
    }
    if (lane == 0) sbest[wid] = best;
    __syncthreads();
    if (tid == 0) {
        ull bb = sbest[0];
        #pragma unroll
        for (int k = 1; k < 4; ++k) bb = sbest[k] < bb ? sbest[k] : bb;
        int c = (int)(unsigned)(bb & 0xffffffffull);
        bxy[b] = make_int2(c / W_, c % W_);
    }
}

// chunked 2-pass suffix scan; bxy staged in LDS once per block (R17-proven)
__global__ __launch_bounds__(256) void k_scan(const int2* __restrict__ bxy, const int* __restrict__ ep,
                                              const int* __restrict__ tp, ushort_t* __restrict__ coefT,
                                              float* __restrict__ T) {
    __shared__ float E[W_];
    __shared__ int2 sb[B_];            // 8KB
    float lr, inv2r2;
    decay_params(ep, tp, lr, inv2r2);
    if (threadIdx.x < W_) {
        float d = (float)threadIdx.x;
        E[threadIdx.x] = __expf(-d * d * inv2r2);
    }
    #pragma unroll
    for (int r = 0; r < 4; ++r) sb[r * 256 + threadIdx.x] = bxy[r * 256 + threadIdx.x];
    __syncthreads();

    int g = blockIdx.x * 256 + threadIdx.x;
    int c = g >> 3, t = g & 7;
    if (c >= NC) return;
    int cy = c / W_, cx = c % W_;
    int base = t * 128;

    float P = 1.0f;
    for (int i = base; i < base + 128; ++i) {
        int2 p = sb[i];
        int dy = abs(p.x - cy), dx = abs(p.y - cx);
        float a = lr * E[dy] * E[dx];
        P *= (1.0f - a);
    }
    int gbase = (threadIdx.x & 63) & ~7;
    float M = 1.0f;
    #pragma unroll
    for (int k = 1; k < 8; ++k) {
        float pk = __shfl(P, gbase + k, 64);
        if (k > t) M *= pk;
    }
    if (t == 0) T[c] = M * P;

    float s = M;
    for (int seg = 15; seg >= 0; --seg) {
        ushort_t buf[8];
        #pragma unroll
        for (int e = 7; e >= 0; --e) {
            int i = base + seg * 8 + e;
            int2 p = sb[i];
            int dy = abs(p.x - cy), dx = abs(p.y - cx);
            float a = lr * E[dy] * E[dx];
            buf[e] = f2bf(a * s);
            s *= (1.0f - a);
        }
        *reinterpret_cast<uint4*>(&coefT[(size_t)c * B_ + base + seg * 8]) =
            *reinterpret_cast<uint4*>(buf);
    }
}

// update GEMM: tile 32 cells x 64 d, BK=64, 4 waves — 2-phase issue-early staging (R17-proven)
__global__ __launch_bounds__(256) void k_update(const ushort_t* __restrict__ coefT, const ushort_t* __restrict__ xhT,
                                                const float* __restrict__ T, const float* __restrict__ w0,
                                                float* __restrict__ out) {
    __shared__ __align__(16) ushort_t As[2][32 * 64];   // 2 x 4KB
    __shared__ __align__(16) ushort_t Bs[2][64 * 64];   // 2 x 8KB
    const int tid = threadIdx.x;
    int orig = blockIdx.y * gridDim.x + blockIdx.x;
    int wgid = xcd_swz(orig, 4 * 313);
    const int d0 = (wgid & 3) * 64;
    const int c0 = (wgid >> 2) * 32;
    const int wid = tid >> 6, lane = tid & 63;
    const int wc = wid >> 1, wd = wid & 1;   // wc: 16-cell half, wd: 32-d half
    const int g4 = lane >> 4, l16 = lane & 15;

    f32x4 acc[2] = {};

    auto STAGE = [&](int buf, int k0) {
        {   // A: 32 rows x 8 units = 256 (one shot)
            int row = tid >> 3, u = tid & 7;
            int ug = (u ^ (row & 7)) * 8;
            int cc = c0 + row; if (cc > NC - 1) cc = NC - 1;
            gl_lds16(&coefT[(size_t)cc * B_ + k0 + ug], &As[buf][(tid & ~63) * 8]);
        }
        #pragma unroll
        for (int r = 0; r < 2; ++r) {   // B: 64 rows x 8 units = 512
            int f = tid + r * 256;
            int row = f >> 3, u = f & 7;
            int ug = (u ^ (row & 7)) * 8;
            gl_lds16(&xhT[(size_t)(d0 + row) * B_ + k0 + ug], &Bs[buf][(f & ~63) * 8]);
        }
    };

    STAGE(0, 0);
    __syncthreads();
    for (int kt = 0; kt < 16; ++kt) {
        int cur = kt & 1;
        if (kt < 15) STAGE(cur ^ 1, (kt + 1) * 64);
        #pragma unroll
        for (int kh = 0; kh < 2; ++kh) {
            int ubase = kh * 4 + g4;
            int rowa = wc * 16 + l16;
            bf16x8 af = *reinterpret_cast<const bf16x8*>(&As[cur][rowa * 64 + ((ubase ^ (rowa & 7)) * 8)]);
            #pragma unroll
            for (int fn = 0; fn < 2; ++fn) {
                int rowb = wd * 32 + fn * 16 + l16;
                bf16x8 bfr = *reinterpret_cast<const bf16x8*>(&Bs[cur][rowb * 64 + ((ubase ^ (rowb & 7)) * 8)]);
                acc[fn] = __builtin_amdgcn_mfma_f32_16x16x32_bf16(af, bfr, acc[fn], 0, 0, 0);
            }
        }
        __syncthreads();
    }

    #pragma unroll
    for (int r = 0; r < 4; ++r) {
        int c = c0 + wc * 16 + g4 * 4 + r;
        if (c < NC) {
            float t = T[c];
            #pragma unroll
            for (int fn = 0; fn < 2; ++fn) {
                int d = d0 + wd * 32 + fn * 16 + l16;
                out[(size_t)c * D_ + d] = fmaf(t, w0[(size_t)c * D_ + d], acc[fn][r]);
            }
        }
    }
}

// ---------- tiny-ws fallback path ----------
__global__ void k_initfix(ull* packed_fix) {
    int i = blockIdx.x * 256 + threadIdx.x;
    if (i < B_) packed_fix[i] = ~0ull;
}
__global__ __launch_bounds__(256) void k_exact_bmu(const float* __restrict__ x, const float* __restrict__ w,
                                                   ull* __restrict__ packed_fix) {
    int b = blockIdx.x;
    int wid = threadIdx.x >> 6, lane = threadIdx.x & 63;
    float4 xv = *reinterpret_cast<const float4*>(&x[(size_t)b * D_ + lane * 4]);
    ull best = ~0ull;
    for (int c = wid; c < NC; c += 4) {
        float4 wv = *reinterpret_cast<const float4*>(&w[(size_t)c * D_ + lane * 4]);
        float p = wv.x * (wv.x - 2.0f * xv.x) + wv.y * (wv.y - 2.0f * xv.y)
                + wv.z * (wv.z - 2.0f * xv.z) + wv.w * (wv.w - 2.0f * xv.w);
        #pragma unroll
        for (int off = 32; off; off >>= 1) p += __shfl_xor(p, off);
        if (lane == 0) {
            ull pk = ((ull)fkey(p) << 32) | (unsigned)c;
            best = pk < best ? pk : best;
        }
    }
    if (lane == 0) atomicMin(&packed_fix[b], best);
}
__global__ void k_decode_force(const ull* __restrict__ packed_fix, float2* __restrict__ xy) {
    int i = blockIdx.x * 256 + threadIdx.x;
    if (i < B_) {
        int c = (int)(unsigned)(packed_fix[i] & 0xffffffffull);
        xy[i] = make_float2((float)(c / W_), (float)(c % W_));
    }
}
__global__ __launch_bounds__(256) void k_update_fallback(const float* __restrict__ x, const float* __restrict__ w0,
                                                         const float2* __restrict__ xy, const int* ep, const int* tp,
                                                         float* __restrict__ out) {
    int c = blockIdx.x;
    int d = threadIdx.x;
    float cyf = (float)(c / W_), cxf = (float)(c % W_);
    float lr, inv2r2;
    decay_params(ep, tp, lr, inv2r2);
    float acc = w0[(size_t)c * D_ + d];
    for (int i = 0; i < B_; ++i) {
        float2 p = xy[i];
        float dy = p.x - cyf, dx = p.y - cxf;
        float a = lr * __expf(-(dy * dy + dx * dx) * inv2r2);
        acc = fmaf(a, x[(size_t)i * D_ + d] - acc, acc);
    }
    out[(size_t)c * D_ + d] = acc;
}

extern "C" void kernel_launch(void* const* d_in, const int* in_sizes, int n_in,
                              void* d_out, int out_size, void* d_ws, size_t ws_size,
                              hipStream_t stream) {
    const float* x = (const float*)d_in[0];
    const float* w = (const float*)d_in[1];
    const int* ep = (const int*)d_in[2];
    const int* tp = (const int*)d_in[3];
    float* out = (float*)d_out;

    char* ws = (char*)d_ws;
    ull* pk1        = (ull*)ws;                      // 8KB    @ 0
    int2* bxy       = (int2*)(ws + 16384);           // 8KB    @ 16K
    float2* xyf     = (float2*)(ws + 16384);         // (fallback alias)
    float* T        = (float*)(ws + 24576);          // 40KB   @ 24K
    float* wnorm    = (float*)(ws + 65536);          // 40.5KB @ 64K (incl +128 pad)
    ushort_t* xhT   = (ushort_t*)(ws + 131072);      // 512KB  @ 128K
    __half* xh      = (__half*)(ws + 655360);        // 512KB
    __half* wh      = (__half*)(ws + 1179648);       // 5.12MB
    ushort_t* coefT = (ushort_t*)(ws + 6553600);     // 20.48MB
    __half* h       = (__half*)(ws + 27262976);      // 20.97MB -> ends 48234496
    ull* pktile     = (ull*)(ws + 48234496);         // 1024*160*8 = 1.31MB
    size_t required = 48234496 + (size_t)B_ * PTS * 8;  // ~49.5MB

    if (ws_size >= required) {
        k_prep<<<NC / 4 + 64 + 1 + 40, 256, 0, stream>>>(w, x, wh, wnorm, xh, xhT, pk1, pktile);
        k_scores_mfma<<<dim3(8, NTC), 512, 0, stream>>>(wh, xh, wnorm, h, pk1, pktile);
        k_fix<<<B_, 256, 0, stream>>>(h, wnorm, x, w, pk1, pktile, bxy);
        k_scan<<<(NC * 8 + 255) / 256, 256, 0, stream>>>(bxy, ep, tp, coefT, T);
        k_update<<<dim3(4, 313), 256, 0, stream>>>(coefT, xhT, T, w, out);
    } else {
        k_initfix<<<4, 256, 0, stream>>>(pk1);
        k_exact_bmu<<<B_, 256, 0, stream>>>(x, w, pk1);
        k_decode_force<<<4, 256, 0, stream>>>(pk1, xyf);
        k_update_fallback<<<NC, 256, 0, stream>>>(x, w, xyf, ep, tp, out);
    }
}

// Round 20
// 83.472 us; speedup vs baseline: 1.0277x; 1.0277x over previous
//
#include <hip/hip_runtime.h>
#include <hip/hip_fp16.h>

typedef unsigned long long ull;
typedef unsigned short ushort_t;
typedef unsigned int u32;
typedef short bf16x8 __attribute__((ext_vector_type(8)));
typedef _Float16 f16x8 __attribute__((ext_vector_type(8)));
typedef float f32x4 __attribute__((ext_vector_type(4)));

#define NC 10000   // H*W cells
#define D_ 256     // input dim
#define B_ 1024    // batch
#define W_ 100     // grid width
#define NTC 157    // scores c-tiles (64 cells each)
#define LD 10240   // padded row stride for h
#define FIXMARGIN 0.06f  // >= 2*eps_score(fp16 mfma scores) — proven R5/R13
#define SHORTCAP 128

// async global->LDS, 16B per lane; LDS dest = wave-uniform base + lane*16
__device__ __forceinline__ void gl_lds16(const void* g, void* l) {
    __builtin_amdgcn_global_load_lds(
        (const __attribute__((address_space(1))) u32*)g,
        (__attribute__((address_space(3))) u32*)l,
        16, 0, 0);
}

// bijective XCD-chunk swizzle (m204)
__device__ __forceinline__ int xcd_swz(int orig, int nwg) {
    int q = nwg >> 3, r = nwg & 7;
    int xcd = orig & 7, off = orig >> 3;
    return (xcd < r ? xcd * (q + 1) : r * (q + 1) + (xcd - r) * q) + off;
}

// monotonic float -> sortable uint mapping
__device__ __forceinline__ unsigned fkey(float f) {
    unsigned u = __float_as_uint(f);
    return (u & 0x80000000u) ? ~u : (u | 0x80000000u);
}
__device__ __forceinline__ float unfkey(unsigned k) {
    unsigned u = (k & 0x80000000u) ? (k ^ 0x80000000u) : ~k;
    return __uint_as_float(u);
}

// exact RNE float -> bf16 bits
__device__ __forceinline__ ushort_t f2bf(float f) {
    unsigned u = __float_as_uint(f);
    unsigned r = (u + 0x7fffu + ((u >> 16) & 1u)) >> 16;
    return (ushort_t)r;
}

__device__ __forceinline__ void decay_params(const int* ep, const int* tp, float& lr, float& inv2r2) {
    double decay = 1.0 - (double)(*ep) / (double)(*tp);
    lr = (float)(0.5 * decay);
    float radius = (float)(50.0 * decay);
    inv2r2 = 1.0f / (2.0f * radius * radius);
}

// fused prep: blocks [0,2500) = w -> wh fp16 + wnorm; [2500,2564) = x -> xh fp16 + xhT bf16;
// block 2564 = init pk1 (~0) + wnorm phantom pad (+inf)
__global__ __launch_bounds__(256) void k_prep(const float* __restrict__ w, const float* __restrict__ x,
                                              __half* __restrict__ wh, float* __restrict__ wnorm,
                                              __half* __restrict__ xh, ushort_t* __restrict__ xhT,
                                              ull* __restrict__ pk1) {
    int bid = blockIdx.x;
    int tid = threadIdx.x;
    if (bid < NC / 4) {
        int cell = bid * 4 + (tid >> 6);
        int lane = tid & 63;
        float4 v = *reinterpret_cast<const float4*>(&w[(size_t)cell * D_ + lane * 4]);
        float s = v.x * v.x + v.y * v.y + v.z * v.z + v.w * v.w;
        __half hb[4];
        float e[4] = {v.x, v.y, v.z, v.w};
        #pragma unroll
        for (int i = 0; i < 4; ++i) hb[i] = __float2half(e[i]);
        *reinterpret_cast<uint2*>(&wh[(size_t)cell * D_ + lane * 4]) = *reinterpret_cast<uint2*>(hb);
        #pragma unroll
        for (int off = 32; off; off >>= 1) s += __shfl_xor(s, off);
        if (lane == 0) wnorm[cell] = s;
    } else if (bid < NC / 4 + 64) {
        __shared__ ushort_t tile[64][65];
        int idx = bid - NC / 4;
        int b0 = (idx & 15) * 64, d0 = (idx >> 4) * 64;
        #pragma unroll
        for (int r = 0; r < 16; ++r) {
            int f = r * 256 + tid;
            int i = f >> 6, j = f & 63;       // i = b-local, j = d-local
            float v = x[(size_t)(b0 + i) * D_ + d0 + j];
            xh[(size_t)(b0 + i) * D_ + d0 + j] = __float2half(v);
            tile[j][i] = f2bf(v);
        }
        __syncthreads();
        #pragma unroll
        for (int r = 0; r < 2; ++r) {
            int f = r * 256 + tid;            // [0,512): 64 d-rows x 8 units
            int row = f >> 3, u = f & 7;
            ushort_t v[8];
            #pragma unroll
            for (int e = 0; e < 8; ++e) v[e] = tile[row][u * 8 + e];
            *reinterpret_cast<uint4*>(&xhT[(size_t)(d0 + row) * B_ + b0 + u * 8]) =
                *reinterpret_cast<uint4*>(v);
        }
    } else {
        #pragma unroll
        for (int k = 0; k < 4; ++k) pk1[tid * 4 + k] = ~0ull;
        if (tid < 128) wnorm[NC + tid] = __builtin_inff();
    }
}

// fp16 scores GEMM: tile 64 cells x 128 batch, BK=64, 8 waves — 2-phase issue-early staging (R18)
__global__ __launch_bounds__(512) void k_scores_mfma(const __half* __restrict__ wh, const __half* __restrict__ xh,
                                                     const float* __restrict__ wnorm, __half* __restrict__ h,
                                                     ull* __restrict__ pk1) {
    __shared__ __align__(16) __half As[2][64 * 64];    // 2 x 8KB
    __shared__ __align__(16) __half Bs[2][128 * 64];   // 2 x 16KB
    const int tid = threadIdx.x;
    int orig = blockIdx.y * gridDim.x + blockIdx.x;
    int wgid = xcd_swz(orig, 8 * NTC);
    const int b0 = (wgid & 7) * 128;
    const int c0 = (wgid >> 3) * 64;
    const int wid = tid >> 6, lane = tid & 63;
    const int wc = wid >> 2;           // 0..1 -> 32-cell half
    const int wb = wid & 3;            // 0..3 -> 32-batch quarter
    const int g4 = lane >> 4, l16 = lane & 15;

    f32x4 acc[2][2] = {};

    auto STAGE = [&](int buf, int k0) {
        {   // A: 64 rows x 8 units = 512 (one shot)
            int row = tid >> 3, u = tid & 7;
            int ug = (u ^ (row & 7)) * 8;
            int cc = c0 + row; if (cc > NC - 1) cc = NC - 1;
            gl_lds16(&wh[(size_t)cc * D_ + k0 + ug], &As[buf][(tid & ~63) * 8]);
        }
        #pragma unroll
        for (int r = 0; r < 2; ++r) {   // B: 128 rows x 8 units = 1024
            int f = tid + r * 512;
            int row = f >> 3, u = f & 7;
            int ug = (u ^ (row & 7)) * 8;
            gl_lds16(&xh[(size_t)(b0 + row) * D_ + k0 + ug], &Bs[buf][(f & ~63) * 8]);
        }
    };

    STAGE(0, 0);
    __syncthreads();
    for (int kt = 0; kt < 4; ++kt) {
        int cur = kt & 1;
        if (kt < 3) STAGE(cur ^ 1, (kt + 1) * 64);   // issue-early: latency overlaps MFMA below
        #pragma unroll
        for (int kh = 0; kh < 2; ++kh) {
            int ubase = kh * 4 + g4;
            f16x8 bfr[2];
            #pragma unroll
            for (int fn = 0; fn < 2; ++fn) {
                int rowb = wb * 32 + fn * 16 + l16;
                bfr[fn] = *reinterpret_cast<const f16x8*>(&Bs[cur][rowb * 64 + ((ubase ^ (rowb & 7)) * 8)]);
            }
            #pragma unroll
            for (int fm = 0; fm < 2; ++fm) {
                int rowa = wc * 32 + fm * 16 + l16;
                f16x8 af = *reinterpret_cast<const f16x8*>(&As[cur][rowa * 64 + ((ubase ^ (rowa & 7)) * 8)]);
                #pragma unroll
                for (int fn = 0; fn < 2; ++fn)
                    acc[fm][fn] = __builtin_amdgcn_mfma_f32_16x16x32_f16(af, bfr[fn], acc[fm][fn], 0, 0, 0);
            }
        }
        __syncthreads();   // drains vmcnt: next buffer ready; cur reads done
    }

    // store h (dot, fp16)
    #pragma unroll
    for (int fm = 0; fm < 2; ++fm) {
        int cb = c0 + wc * 32 + fm * 16 + g4 * 4;
        #pragma unroll
        for (int fn = 0; fn < 2; ++fn) {
            int b = b0 + wb * 32 + fn * 16 + l16;
            __half hv[4];
            #pragma unroll
            for (int r = 0; r < 4; ++r) hv[r] = __float2half(acc[fm][fn][r]);
            *reinterpret_cast<uint2*>(&h[(size_t)b * LD + cb]) = *reinterpret_cast<uint2*>(hv);
        }
    }

    // fused min1 (wnorm pad = +inf covers phantom cells)
    ull best[2] = {~0ull, ~0ull};
    #pragma unroll
    for (int fm = 0; fm < 2; ++fm) {
        int cb = c0 + wc * 32 + fm * 16 + g4 * 4;
        float4 wn4 = *reinterpret_cast<const float4*>(&wnorm[cb]);
        float wna[4] = {wn4.x, wn4.y, wn4.z, wn4.w};
        #pragma unroll
        for (int fn = 0; fn < 2; ++fn)
            #pragma unroll
            for (int r = 0; r < 4; ++r) {
                float s = wna[r] - 2.0f * acc[fm][fn][r];
                ull p = ((ull)fkey(s) << 32) | (unsigned)(cb + r);
                if (p < best[fn]) best[fn] = p;
            }
    }
    #pragma unroll
    for (int fn = 0; fn < 2; ++fn) {
        ull o = __shfl_xor(best[fn], 16); best[fn] = o < best[fn] ? o : best[fn];
        o = __shfl_xor(best[fn], 32);     best[fn] = o < best[fn] ? o : best[fn];
    }
    if (g4 == 0) {
        atomicMin(&pk1[b0 + wb * 32 + l16], best[0]);
        atomicMin(&pk1[b0 + wb * 32 + 16 + l16], best[1]);
    }
}

// always-on fix (R5/R13-proven, unchanged)
__global__ __launch_bounds__(256) void k_fix(const __half* __restrict__ h, const float* __restrict__ wnorm,
                                             const float* __restrict__ x, const float* __restrict__ w,
                                             const ull* __restrict__ pk1, int2* __restrict__ bxy) {
    __shared__ int cnt;
    __shared__ int cand[SHORTCAP];
    __shared__ ull sbest[4];
    int b = blockIdx.x, tid = threadIdx.x;
    if (tid == 0) cnt = 0;
    __syncthreads();
    float thr = unfkey((unsigned)(pk1[b] >> 32)) + FIXMARGIN;
    for (int ch = 0; ch < 10; ++ch) {
        int c = ch * 1024 + tid * 4;
        if (c < NC) {
            __half hv[4];
            *reinterpret_cast<uint2*>(hv) = *reinterpret_cast<const uint2*>(&h[(size_t)b * LD + c]);
            float4 wn = *reinterpret_cast<const float4*>(&wnorm[c]);
            float we[4] = {wn.x, wn.y, wn.z, wn.w};
            #pragma unroll
            for (int e = 0; e < 4; ++e) {
                float s = we[e] - 2.0f * (float)hv[e];
                if (s <= thr) {
                    int p = atomicAdd(&cnt, 1);
                    if (p < SHORTCAP) cand[p] = c + e;
                }
            }
        }
    }
    __syncthreads();
    int n = cnt;
    int wid = tid >> 6, lane = tid & 63;
    float4 xv = *reinterpret_cast<const float4*>(&x[(size_t)b * D_ + lane * 4]);
    ull best = ~0ull;
    if (n <= SHORTCAP) {
        for (int i = wid; i < n; i += 4) {
            int c = cand[i];
            float4 wv = *reinterpret_cast<const float4*>(&w[(size_t)c * D_ + lane * 4]);
            float p = wv.x * (wv.x - 2.0f * xv.x) + wv.y * (wv.y - 2.0f * xv.y)
                    + wv.z * (wv.z - 2.0f * xv.z) + wv.w * (wv.w - 2.0f * xv.w);
            #pragma unroll
            for (int off = 32; off; off >>= 1) p += __shfl_xor(p, off);
            if (lane == 0) {
                ull pk = ((ull)fkey(p) << 32) | (unsigned)c;
                best = pk < best ? pk : best;
            }
        }
    } else {
        for (int c = wid; c < NC; c += 4) {
            float4 wv = *reinterpret_cast<const float4*>(&w[(size_t)c * D_ + lane * 4]);
            float p = wv.x * (wv.x - 2.0f * xv.x) + wv.y * (wv.y - 2.0f * xv.y)
                    + wv.z * (wv.z - 2.0f * xv.z) + wv.w * (wv.w - 2.0f * xv.w);
            #pragma unroll
            for (int off = 32; off; off >>= 1) p += __shfl_xor(p, off);
            if (lane == 0) {
                ull pk = ((ull)fkey(p) << 32) | (unsigned)c;
                best = pk < best ? pk : best;
            }
        }
    }
    if (lane == 0) sbest[wid] = best;
    __syncthreads();
    if (tid == 0) {
        ull bb = sbest[0];
        #pragma unroll
        for (int k = 1; k < 4; ++k) bb = sbest[k] < bb ? sbest[k] : bb;
        int c = (int)(unsigned)(bb & 0xffffffffull);
        bxy[b] = make_int2(c / W_, c % W_);
    }
}

// chunked 2-pass suffix scan: 16 threads/cell, 64-sample chunks (R16-proven numerics),
// bxy LDS-staged (R17-proven); grid 625 blocks (~2.4/CU) for latency hiding
__global__ __launch_bounds__(256) void k_scan(const int2* __restrict__ bxy, const int* __restrict__ ep,
                                              const int* __restrict__ tp, ushort_t* __restrict__ coefT,
                                              float* __restrict__ T) {
    __shared__ float E[W_];
    __shared__ int2 sb[B_];            // 8KB
    float lr, inv2r2;
    decay_params(ep, tp, lr, inv2r2);
    if (threadIdx.x < W_) {
        float d = (float)threadIdx.x;
        E[threadIdx.x] = __expf(-d * d * inv2r2);
    }
    #pragma unroll
    for (int r = 0; r < 4; ++r) sb[r * 256 + threadIdx.x] = bxy[r * 256 + threadIdx.x];
    __syncthreads();

    int tid = threadIdx.x, lane = tid & 63;
    int cl = tid >> 4;                 // local cell 0..15
    int t = tid & 15;                  // chunk 0..15 (64 samples each)
    int c = blockIdx.x * 16 + cl;
    if (c >= NC) return;
    int cy = c / W_, cx = c % W_;
    int base = t * 64;

    // pass 1: chunk product
    float P = 1.0f;
    for (int i = base; i < base + 64; ++i) {
        int2 p = sb[i];
        int dy = abs(p.x - cy), dx = abs(p.y - cx);
        P *= (1.0f - lr * E[dy] * E[dx]);
    }
    // suffix product across 16-lane group
    int gbase = lane & ~15;
    float M = 1.0f;
    #pragma unroll
    for (int k = 1; k < 16; ++k) {
        float pk = __shfl(P, gbase + k, 64);
        if (k > t) M *= pk;
    }
    if (t == 0) T[c] = M * P;

    // pass 2: descending, coef = a_i * s
    float s = M;
    for (int seg = 7; seg >= 0; --seg) {
        ushort_t buf[8];
        #pragma unroll
        for (int e = 7; e >= 0; --e) {
            int i = base + seg * 8 + e;
            int2 p = sb[i];
            int dy = abs(p.x - cy), dx = abs(p.y - cx);
            float a = lr * E[dy] * E[dx];
            buf[e] = f2bf(a * s);
            s *= (1.0f - a);
        }
        *reinterpret_cast<uint4*>(&coefT[(size_t)c * B_ + base + seg * 8]) =
            *reinterpret_cast<uint4*>(buf);
    }
}

// update GEMM: tile 32 cells x 64 d, BK=64, 4 waves — 2-phase issue-early staging (R17-proven)
__global__ __launch_bounds__(256) void k_update(const ushort_t* __restrict__ coefT, const ushort_t* __restrict__ xhT,
                                                const float* __restrict__ T, const float* __restrict__ w0,
                                                float* __restrict__ out) {
    __shared__ __align__(16) ushort_t As[2][32 * 64];   // 2 x 4KB
    __shared__ __align__(16) ushort_t Bs[2][64 * 64];   // 2 x 8KB
    const int tid = threadIdx.x;
    int orig = blockIdx.y * gridDim.x + blockIdx.x;
    int wgid = xcd_swz(orig, 4 * 313);
    const int d0 = (wgid & 3) * 64;
    const int c0 = (wgid >> 2) * 32;
    const int wid = tid >> 6, lane = tid & 63;
    const int wc = wid >> 1, wd = wid & 1;   // wc: 16-cell half, wd: 32-d half
    const int g4 = lane >> 4, l16 = lane & 15;

    f32x4 acc[2] = {};

    auto STAGE = [&](int buf, int k0) {
        {   // A: 32 rows x 8 units = 256 (one shot)
            int row = tid >> 3, u = tid & 7;
            int ug = (u ^ (row & 7)) * 8;
            int cc = c0 + row; if (cc > NC - 1) cc = NC - 1;
            gl_lds16(&coefT[(size_t)cc * B_ + k0 + ug], &As[buf][(tid & ~63) * 8]);
        }
        #pragma unroll
        for (int r = 0; r < 2; ++r) {   // B: 64 rows x 8 units = 512
            int f = tid + r * 256;
            int row = f >> 3, u = f & 7;
            int ug = (u ^ (row & 7)) * 8;
            gl_lds16(&xhT[(size_t)(d0 + row) * B_ + k0 + ug], &Bs[buf][(f & ~63) * 8]);
        }
    };

    STAGE(0, 0);
    __syncthreads();
    for (int kt = 0; kt < 16; ++kt) {
        int cur = kt & 1;
        if (kt < 15) STAGE(cur ^ 1, (kt + 1) * 64);
        #pragma unroll
        for (int kh = 0; kh < 2; ++kh) {
            int ubase = kh * 4 + g4;
            int rowa = wc * 16 + l16;
            bf16x8 af = *reinterpret_cast<const bf16x8*>(&As[cur][rowa * 64 + ((ubase ^ (rowa & 7)) * 8)]);
            #pragma unroll
            for (int fn = 0; fn < 2; ++fn) {
                int rowb = wd * 32 + fn * 16 + l16;
                bf16x8 bfr = *reinterpret_cast<const bf16x8*>(&Bs[cur][rowb * 64 + ((ubase ^ (rowb & 7)) * 8)]);
                acc[fn] = __builtin_amdgcn_mfma_f32_16x16x32_bf16(af, bfr, acc[fn], 0, 0, 0);
            }
        }
        __syncthreads();
    }

    #pragma unroll
    for (int r = 0; r < 4; ++r) {
        int c = c0 + wc * 16 + g4 * 4 + r;
        if (c < NC) {
            float t = T[c];
            #pragma unroll
            for (int fn = 0; fn < 2; ++fn) {
                int d = d0 + wd * 32 + fn * 16 + l16;
                out[(size_t)c * D_ + d] = fmaf(t, w0[(size_t)c * D_ + d], acc[fn][r]);
            }
        }
    }
}

// ---------- tiny-ws fallback path ----------
__global__ void k_initfix(ull* packed_fix) {
    int i = blockIdx.x * 256 + threadIdx.x;
    if (i < B_) packed_fix[i] = ~0ull;
}
__global__ __launch_bounds__(256) void k_exact_bmu(const float* __restrict__ x, const float* __restrict__ w,
                                                   ull* __restrict__ packed_fix) {
    int b = blockIdx.x;
    int wid = threadIdx.x >> 6, lane = threadIdx.x & 63;
    float4 xv = *reinterpret_cast<const float4*>(&x[(size_t)b * D_ + lane * 4]);
    ull best = ~0ull;
    for (int c = wid; c < NC; c += 4) {
        float4 wv = *reinterpret_cast<const float4*>(&w[(size_t)c * D_ + lane * 4]);
        float p = wv.x * (wv.x - 2.0f * xv.x) + wv.y * (wv.y - 2.0f * xv.y)
                + wv.z * (wv.z - 2.0f * xv.z) + wv.w * (wv.w - 2.0f * xv.w);
        #pragma unroll
        for (int off = 32; off; off >>= 1) p += __shfl_xor(p, off);
        if (lane == 0) {
            ull pk = ((ull)fkey(p) << 32) | (unsigned)c;
            best = pk < best ? pk : best;
        }
    }
    if (lane == 0) atomicMin(&packed_fix[b], best);
}
__global__ void k_decode_force(const ull* __restrict__ packed_fix, float2* __restrict__ xy) {
    int i = blockIdx.x * 256 + threadIdx.x;
    if (i < B_) {
        int c = (int)(unsigned)(packed_fix[i] & 0xffffffffull);
        xy[i] = make_float2((float)(c / W_), (float)(c % W_));
    }
}
__global__ __launch_bounds__(256) void k_update_fallback(const float* __restrict__ x, const float* __restrict__ w0,
                                                         const float2* __restrict__ xy, const int* ep, const int* tp,
                                                         float* __restrict__ out) {
    int c = blockIdx.x;
    int d = threadIdx.x;
    float cyf = (float)(c / W_), cxf = (float)(c % W_);
    float lr, inv2r2;
    decay_params(ep, tp, lr, inv2r2);
    float acc = w0[(size_t)c * D_ + d];
    for (int i = 0; i < B_; ++i) {
        float2 p = xy[i];
        float dy = p.x - cyf, dx = p.y - cxf;
        float a = lr * __expf(-(dy * dy + dx * dx) * inv2r2);
        acc = fmaf(a, x[(size_t)i * D_ + d] - acc, acc);
    }
    out[(size_t)c * D_ + d] = acc;
}

extern "C" void kernel_launch(void* const* d_in, const int* in_sizes, int n_in,
                              void* d_out, int out_size, void* d_ws, size_t ws_size,
                              hipStream_t stream) {
    const float* x = (const float*)d_in[0];
    const float* w = (const float*)d_in[1];
    const int* ep = (const int*)d_in[2];
    const int* tp = (const int*)d_in[3];
    float* out = (float*)d_out;

    char* ws = (char*)d_ws;
    ull* pk1        = (ull*)ws;                      // 8KB    @ 0
    int2* bxy       = (int2*)(ws + 16384);           // 8KB    @ 16K
    float2* xyf     = (float2*)(ws + 16384);         // (fallback alias)
    float* T        = (float*)(ws + 24576);          // 40KB   @ 24K
    float* wnorm    = (float*)(ws + 65536);          // 40.5KB @ 64K (incl +128 pad)
    ushort_t* xhT   = (ushort_t*)(ws + 131072);      // 512KB  @ 128K
    __half* xh      = (__half*)(ws + 655360);        // 512KB
    __half* wh      = (__half*)(ws + 1179648);       // 5.12MB
    ushort_t* coefT = (ushort_t*)(ws + 6553600);     // 20.48MB
    __half* h       = (__half*)(ws + 27262976);      // 20.97MB
    size_t required = 27262976 + (size_t)B_ * LD * 2;  // ~48.2MB

    if (ws_size >= required) {
        k_prep<<<NC / 4 + 64 + 1, 256, 0, stream>>>(w, x, wh, wnorm, xh, xhT, pk1);
        k_scores_mfma<<<dim3(8, NTC), 512, 0, stream>>>(wh, xh, wnorm, h, pk1);
        k_fix<<<B_, 256, 0, stream>>>(h, wnorm, x, w, pk1, bxy);
        k_scan<<<625, 256, 0, stream>>>(bxy, ep, tp, coefT, T);
        k_update<<<dim3(4, 313), 256, 0, stream>>>(coefT, xhT, T, w, out);
    } else {
        k_initfix<<<4, 256, 0, stream>>>(pk1);
        k_exact_bmu<<<B_, 256, 0, stream>>>(x, w, pk1);
        k_decode_force<<<4, 256, 0, stream>>>(pk1, xyf);
        k_update_fallback<<<NC, 256, 0, stream>>>(x, w, xyf, ep, tp, out);
    }
}

// Round 21
// 77.788 us; speedup vs baseline: 1.1028x; 1.0731x over previous
//
#include <hip/hip_runtime.h>
#include <hip/hip_fp16.h>

typedef unsigned long long ull;
typedef unsigned short ushort_t;
typedef unsigned int u32;
typedef short bf16x8 __attribute__((ext_vector_type(8)));
typedef _Float16 f16x8 __attribute__((ext_vector_type(8)));
typedef float f32x4 __attribute__((ext_vector_type(4)));

#define NC 10000   // H*W cells
#define D_ 256     // input dim
#define B_ 1024    // batch
#define W_ 100     // grid width
#define NTC 157    // scores c-tiles (64 cells each)
#define LD 10240   // padded row stride for h
#define FIXMARGIN 0.06f  // >= 2*eps_score(fp16 mfma scores) — proven R5/R13
#define SHORTCAP 128

// async global->LDS, 16B per lane; LDS dest = wave-uniform base + lane*16
__device__ __forceinline__ void gl_lds16(const void* g, void* l) {
    __builtin_amdgcn_global_load_lds(
        (const __attribute__((address_space(1))) u32*)g,
        (__attribute__((address_space(3))) u32*)l,
        16, 0, 0);
}

// bijective XCD-chunk swizzle (m204)
__device__ __forceinline__ int xcd_swz(int orig, int nwg) {
    int q = nwg >> 3, r = nwg & 7;
    int xcd = orig & 7, off = orig >> 3;
    return (xcd < r ? xcd * (q + 1) : r * (q + 1) + (xcd - r) * q) + off;
}

// monotonic float -> sortable uint mapping
__device__ __forceinline__ unsigned fkey(float f) {
    unsigned u = __float_as_uint(f);
    return (u & 0x80000000u) ? ~u : (u | 0x80000000u);
}
__device__ __forceinline__ float unfkey(unsigned k) {
    unsigned u = (k & 0x80000000u) ? (k ^ 0x80000000u) : ~k;
    return __uint_as_float(u);
}

// exact RNE float -> bf16 bits
__device__ __forceinline__ ushort_t f2bf(float f) {
    unsigned u = __float_as_uint(f);
    unsigned r = (u + 0x7fffu + ((u >> 16) & 1u)) >> 16;
    return (ushort_t)r;
}

__device__ __forceinline__ void decay_params(const int* ep, const int* tp, float& lr, float& inv2r2) {
    double decay = 1.0 - (double)(*ep) / (double)(*tp);
    lr = (float)(0.5 * decay);
    float radius = (float)(50.0 * decay);
    inv2r2 = 1.0f / (2.0f * radius * radius);
}

// fused prep: blocks [0,2500) = w -> wh fp16 + wnorm; [2500,2564) = x -> xh fp16 + xhT bf16;
// block 2564 = init pk1 (~0) + wnorm phantom pad (+inf)
__global__ __launch_bounds__(256) void k_prep(const float* __restrict__ w, const float* __restrict__ x,
                                              __half* __restrict__ wh, float* __restrict__ wnorm,
                                              __half* __restrict__ xh, ushort_t* __restrict__ xhT,
                                              ull* __restrict__ pk1) {
    int bid = blockIdx.x;
    int tid = threadIdx.x;
    if (bid < NC / 4) {
        int cell = bid * 4 + (tid >> 6);
        int lane = tid & 63;
        float4 v = *reinterpret_cast<const float4*>(&w[(size_t)cell * D_ + lane * 4]);
        float s = v.x * v.x + v.y * v.y + v.z * v.z + v.w * v.w;
        __half hb[4];
        float e[4] = {v.x, v.y, v.z, v.w};
        #pragma unroll
        for (int i = 0; i < 4; ++i) hb[i] = __float2half(e[i]);
        *reinterpret_cast<uint2*>(&wh[(size_t)cell * D_ + lane * 4]) = *reinterpret_cast<uint2*>(hb);
        #pragma unroll
        for (int off = 32; off; off >>= 1) s += __shfl_xor(s, off);
        if (lane == 0) wnorm[cell] = s;
    } else if (bid < NC / 4 + 64) {
        __shared__ ushort_t tile[64][65];
        int idx = bid - NC / 4;
        int b0 = (idx & 15) * 64, d0 = (idx >> 4) * 64;
        #pragma unroll
        for (int r = 0; r < 16; ++r) {
            int f = r * 256 + tid;
            int i = f >> 6, j = f & 63;       // i = b-local, j = d-local
            float v = x[(size_t)(b0 + i) * D_ + d0 + j];
            xh[(size_t)(b0 + i) * D_ + d0 + j] = __float2half(v);
            tile[j][i] = f2bf(v);
        }
        __syncthreads();
        #pragma unroll
        for (int r = 0; r < 2; ++r) {
            int f = r * 256 + tid;            // [0,512): 64 d-rows x 8 units
            int row = f >> 3, u = f & 7;
            ushort_t v[8];
            #pragma unroll
            for (int e = 0; e < 8; ++e) v[e] = tile[row][u * 8 + e];
            *reinterpret_cast<uint4*>(&xhT[(size_t)(d0 + row) * B_ + b0 + u * 8]) =
                *reinterpret_cast<uint4*>(v);
        }
    } else {
        #pragma unroll
        for (int k = 0; k < 4; ++k) pk1[tid * 4 + k] = ~0ull;
        if (tid < 128) wnorm[NC + tid] = __builtin_inff();
    }
}

// fp16 scores GEMM: tile 64 cells x 128 batch, BK=64, 8 waves — 2-PHASE issue-early staging
__global__ __launch_bounds__(512) void k_scores_mfma(const __half* __restrict__ wh, const __half* __restrict__ xh,
                                                     const float* __restrict__ wnorm, __half* __restrict__ h,
                                                     ull* __restrict__ pk1) {
    __shared__ __align__(16) __half As[2][64 * 64];    // 2 x 8KB
    __shared__ __align__(16) __half Bs[2][128 * 64];   // 2 x 16KB
    const int tid = threadIdx.x;
    int orig = blockIdx.y * gridDim.x + blockIdx.x;
    int wgid = xcd_swz(orig, 8 * NTC);
    const int b0 = (wgid & 7) * 128;
    const int c0 = (wgid >> 3) * 64;
    const int wid = tid >> 6, lane = tid & 63;
    const int wc = wid >> 2;           // 0..1 -> 32-cell half
    const int wb = wid & 3;            // 0..3 -> 32-batch quarter
    const int g4 = lane >> 4, l16 = lane & 15;

    f32x4 acc[2][2] = {};

    auto STAGE = [&](int buf, int k0) {
        {   // A: 64 rows x 8 units = 512 (one shot)
            int row = tid >> 3, u = tid & 7;
            int ug = (u ^ (row & 7)) * 8;
            int cc = c0 + row; if (cc > NC - 1) cc = NC - 1;
            gl_lds16(&wh[(size_t)cc * D_ + k0 + ug], &As[buf][(tid & ~63) * 8]);
        }
        #pragma unroll
        for (int r = 0; r < 2; ++r) {   // B: 128 rows x 8 units = 1024
            int f = tid + r * 512;
            int row = f >> 3, u = f & 7;
            int ug = (u ^ (row & 7)) * 8;
            gl_lds16(&xh[(size_t)(b0 + row) * D_ + k0 + ug], &Bs[buf][(f & ~63) * 8]);
        }
    };

    STAGE(0, 0);
    __syncthreads();
    for (int kt = 0; kt < 4; ++kt) {
        int cur = kt & 1;
        if (kt < 3) STAGE(cur ^ 1, (kt + 1) * 64);   // issue-early: latency overlaps MFMA below
        #pragma unroll
        for (int kh = 0; kh < 2; ++kh) {
            int ubase = kh * 4 + g4;
            f16x8 bfr[2];
            #pragma unroll
            for (int fn = 0; fn < 2; ++fn) {
                int rowb = wb * 32 + fn * 16 + l16;
                bfr[fn] = *reinterpret_cast<const f16x8*>(&Bs[cur][rowb * 64 + ((ubase ^ (rowb & 7)) * 8)]);
            }
            #pragma unroll
            for (int fm = 0; fm < 2; ++fm) {
                int rowa = wc * 32 + fm * 16 + l16;
                f16x8 af = *reinterpret_cast<const f16x8*>(&As[cur][rowa * 64 + ((ubase ^ (rowa & 7)) * 8)]);
                #pragma unroll
                for (int fn = 0; fn < 2; ++fn)
                    acc[fm][fn] = __builtin_amdgcn_mfma_f32_16x16x32_f16(af, bfr[fn], acc[fm][fn], 0, 0, 0);
            }
        }
        __syncthreads();   // drains vmcnt: next buffer ready; cur reads done
    }

    // store h (dot, fp16)
    #pragma unroll
    for (int fm = 0; fm < 2; ++fm) {
        int cb = c0 + wc * 32 + fm * 16 + g4 * 4;
        #pragma unroll
        for (int fn = 0; fn < 2; ++fn) {
            int b = b0 + wb * 32 + fn * 16 + l16;
            __half hv[4];
            #pragma unroll
            for (int r = 0; r < 4; ++r) hv[r] = __float2half(acc[fm][fn][r]);
            *reinterpret_cast<uint2*>(&h[(size_t)b * LD + cb]) = *reinterpret_cast<uint2*>(hv);
        }
    }

    // fused min1 (wnorm pad = +inf covers phantom cells)
    ull best[2] = {~0ull, ~0ull};
    #pragma unroll
    for (int fm = 0; fm < 2; ++fm) {
        int cb = c0 + wc * 32 + fm * 16 + g4 * 4;
        float4 wn4 = *reinterpret_cast<const float4*>(&wnorm[cb]);
        float wna[4] = {wn4.x, wn4.y, wn4.z, wn4.w};
        #pragma unroll
        for (int fn = 0; fn < 2; ++fn)
            #pragma unroll
            for (int r = 0; r < 4; ++r) {
                float s = wna[r] - 2.0f * acc[fm][fn][r];
                ull p = ((ull)fkey(s) << 32) | (unsigned)(cb + r);
                if (p < best[fn]) best[fn] = p;
            }
    }
    #pragma unroll
    for (int fn = 0; fn < 2; ++fn) {
        ull o = __shfl_xor(best[fn], 16); best[fn] = o < best[fn] ? o : best[fn];
        o = __shfl_xor(best[fn], 32);     best[fn] = o < best[fn] ? o : best[fn];
    }
    if (g4 == 0) {
        atomicMin(&pk1[b0 + wb * 32 + l16], best[0]);
        atomicMin(&pk1[b0 + wb * 32 + 16 + l16], best[1]);
    }
}

// always-on fix (R5/R13-proven, unchanged)
__global__ __launch_bounds__(256) void k_fix(const __half* __restrict__ h, const float* __restrict__ wnorm,
                                             const float* __restrict__ x, const float* __restrict__ w,
                                             const ull* __restrict__ pk1, int2* __restrict__ bxy) {
    __shared__ int cnt;
    __shared__ int cand[SHORTCAP];
    __shared__ ull sbest[4];
    int b = blockIdx.x, tid = threadIdx.x;
    if (tid == 0) cnt = 0;
    __syncthreads();
    float thr = unfkey((unsigned)(pk1[b] >> 32)) + FIXMARGIN;
    for (int ch = 0; ch < 10; ++ch) {
        int c = ch * 1024 + tid * 4;
        if (c < NC) {
            __half hv[4];
            *reinterpret_cast<uint2*>(hv) = *reinterpret_cast<const uint2*>(&h[(size_t)b * LD + c]);
            float4 wn = *reinterpret_cast<const float4*>(&wnorm[c]);
            float we[4] = {wn.x, wn.y, wn.z, wn.w};
            #pragma unroll
            for (int e = 0; e < 4; ++e) {
                float s = we[e] - 2.0f * (float)hv[e];
                if (s <= thr) {
                    int p = atomicAdd(&cnt, 1);
                    if (p < SHORTCAP) cand[p] = c + e;
                }
            }
        }
    }
    __syncthreads();
    int n = cnt;
    int wid = tid >> 6, lane = tid & 63;
    float4 xv = *reinterpret_cast<const float4*>(&x[(size_t)b * D_ + lane * 4]);
    ull best = ~0ull;
    if (n <= SHORTCAP) {
        for (int i = wid; i < n; i += 4) {
            int c = cand[i];
            float4 wv = *reinterpret_cast<const float4*>(&w[(size_t)c * D_ + lane * 4]);
            float p = wv.x * (wv.x - 2.0f * xv.x) + wv.y * (wv.y - 2.0f * xv.y)
                    + wv.z * (wv.z - 2.0f * xv.z) + wv.w * (wv.w - 2.0f * xv.w);
            #pragma unroll
            for (int off = 32; off; off >>= 1) p += __shfl_xor(p, off);
            if (lane == 0) {
                ull pk = ((ull)fkey(p) << 32) | (unsigned)c;
                best = pk < best ? pk : best;
            }
        }
    } else {
        for (int c = wid; c < NC; c += 4) {
            float4 wv = *reinterpret_cast<const float4*>(&w[(size_t)c * D_ + lane * 4]);
            float p = wv.x * (wv.x - 2.0f * xv.x) + wv.y * (wv.y - 2.0f * xv.y)
                    + wv.z * (wv.z - 2.0f * xv.z) + wv.w * (wv.w - 2.0f * xv.w);
            #pragma unroll
            for (int off = 32; off; off >>= 1) p += __shfl_xor(p, off);
            if (lane == 0) {
                ull pk = ((ull)fkey(p) << 32) | (unsigned)c;
                best = pk < best ? pk : best;
            }
        }
    }
    if (lane == 0) sbest[wid] = best;
    __syncthreads();
    if (tid == 0) {
        ull bb = sbest[0];
        #pragma unroll
        for (int k = 1; k < 4; ++k) bb = sbest[k] < bb ? sbest[k] : bb;
        int c = (int)(unsigned)(bb & 0xffffffffull);
        bxy[b] = make_int2(c / W_, c % W_);
    }
}

// chunked 2-pass suffix scan; bxy staged in LDS once per block (R17-proven)
__global__ __launch_bounds__(256) void k_scan(const int2* __restrict__ bxy, const int* __restrict__ ep,
                                              const int* __restrict__ tp, ushort_t* __restrict__ coefT,
                                              float* __restrict__ T) {
    __shared__ float E[W_];
    __shared__ int2 sb[B_];            // 8KB
    float lr, inv2r2;
    decay_params(ep, tp, lr, inv2r2);
    if (threadIdx.x < W_) {
        float d = (float)threadIdx.x;
        E[threadIdx.x] = __expf(-d * d * inv2r2);
    }
    #pragma unroll
    for (int r = 0; r < 4; ++r) sb[r * 256 + threadIdx.x] = bxy[r * 256 + threadIdx.x];
    __syncthreads();

    int g = blockIdx.x * 256 + threadIdx.x;
    int c = g >> 3, t = g & 7;
    if (c >= NC) return;
    int cy = c / W_, cx = c % W_;
    int base = t * 128;

    float P = 1.0f;
    for (int i = base; i < base + 128; ++i) {
        int2 p = sb[i];
        int dy = abs(p.x - cy), dx = abs(p.y - cx);
        float a = lr * E[dy] * E[dx];
        P *= (1.0f - a);
    }
    int gbase = (threadIdx.x & 63) & ~7;
    float M = 1.0f;
    #pragma unroll
    for (int k = 1; k < 8; ++k) {
        float pk = __shfl(P, gbase + k, 64);
        if (k > t) M *= pk;
    }
    if (t == 0) T[c] = M * P;

    float s = M;
    for (int seg = 15; seg >= 0; --seg) {
        ushort_t buf[8];
        #pragma unroll
        for (int e = 7; e >= 0; --e) {
            int i = base + seg * 8 + e;
            int2 p = sb[i];
            int dy = abs(p.x - cy), dx = abs(p.y - cx);
            float a = lr * E[dy] * E[dx];
            buf[e] = f2bf(a * s);
            s *= (1.0f - a);
        }
        *reinterpret_cast<uint4*>(&coefT[(size_t)c * B_ + base + seg * 8]) =
            *reinterpret_cast<uint4*>(buf);
    }
}

// update GEMM: tile 32 cells x 64 d, BK=64, 4 waves — 2-phase issue-early staging (R17-proven)
__global__ __launch_bounds__(256) void k_update(const ushort_t* __restrict__ coefT, const ushort_t* __restrict__ xhT,
                                                const float* __restrict__ T, const float* __restrict__ w0,
                                                float* __restrict__ out) {
    __shared__ __align__(16) ushort_t As[2][32 * 64];   // 2 x 4KB
    __shared__ __align__(16) ushort_t Bs[2][64 * 64];   // 2 x 8KB
    const int tid = threadIdx.x;
    int orig = blockIdx.y * gridDim.x + blockIdx.x;
    int wgid = xcd_swz(orig, 4 * 313);
    const int d0 = (wgid & 3) * 64;
    const int c0 = (wgid >> 2) * 32;
    const int wid = tid >> 6, lane = tid & 63;
    const int wc = wid >> 1, wd = wid & 1;   // wc: 16-cell half, wd: 32-d half
    const int g4 = lane >> 4, l16 = lane & 15;

    f32x4 acc[2] = {};

    auto STAGE = [&](int buf, int k0) {
        {   // A: 32 rows x 8 units = 256 (one shot)
            int row = tid >> 3, u = tid & 7;
            int ug = (u ^ (row & 7)) * 8;
            int cc = c0 + row; if (cc > NC - 1) cc = NC - 1;
            gl_lds16(&coefT[(size_t)cc * B_ + k0 + ug], &As[buf][(tid & ~63) * 8]);
        }
        #pragma unroll
        for (int r = 0; r < 2; ++r) {   // B: 64 rows x 8 units = 512
            int f = tid + r * 256;
            int row = f >> 3, u = f & 7;
            int ug = (u ^ (row & 7)) * 8;
            gl_lds16(&xhT[(size_t)(d0 + row) * B_ + k0 + ug], &Bs[buf][(f & ~63) * 8]);
        }
    };

    STAGE(0, 0);
    __syncthreads();
    for (int kt = 0; kt < 16; ++kt) {
        int cur = kt & 1;
        if (kt < 15) STAGE(cur ^ 1, (kt + 1) * 64);
        #pragma unroll
        for (int kh = 0; kh < 2; ++kh) {
            int ubase = kh * 4 + g4;
            int rowa = wc * 16 + l16;
            bf16x8 af = *reinterpret_cast<const bf16x8*>(&As[cur][rowa * 64 + ((ubase ^ (rowa & 7)) * 8)]);
            #pragma unroll
            for (int fn = 0; fn < 2; ++fn) {
                int rowb = wd * 32 + fn * 16 + l16;
                bf16x8 bfr = *reinterpret_cast<const bf16x8*>(&Bs[cur][rowb * 64 + ((ubase ^ (rowb & 7)) * 8)]);
                acc[fn] = __builtin_amdgcn_mfma_f32_16x16x32_bf16(af, bfr, acc[fn], 0, 0, 0);
            }
        }
        __syncthreads();
    }

    #pragma unroll
    for (int r = 0; r < 4; ++r) {
        int c = c0 + wc * 16 + g4 * 4 + r;
        if (c < NC) {
            float t = T[c];
            #pragma unroll
            for (int fn = 0; fn < 2; ++fn) {
                int d = d0 + wd * 32 + fn * 16 + l16;
                out[(size_t)c * D_ + d] = fmaf(t, w0[(size_t)c * D_ + d], acc[fn][r]);
            }
        }
    }
}

// ---------- tiny-ws fallback path ----------
__global__ void k_initfix(ull* packed_fix) {
    int i = blockIdx.x * 256 + threadIdx.x;
    if (i < B_) packed_fix[i] = ~0ull;
}
__global__ __launch_bounds__(256) void k_exact_bmu(const float* __restrict__ x, const float* __restrict__ w,
                                                   ull* __restrict__ packed_fix) {
    int b = blockIdx.x;
    int wid = threadIdx.x >> 6, lane = threadIdx.x & 63;
    float4 xv = *reinterpret_cast<const float4*>(&x[(size_t)b * D_ + lane * 4]);
    ull best = ~0ull;
    for (int c = wid; c < NC; c += 4) {
        float4 wv = *reinterpret_cast<const float4*>(&w[(size_t)c * D_ + lane * 4]);
        float p = wv.x * (wv.x - 2.0f * xv.x) + wv.y * (wv.y - 2.0f * xv.y)
                + wv.z * (wv.z - 2.0f * xv.z) + wv.w * (wv.w - 2.0f * xv.w);
        #pragma unroll
        for (int off = 32; off; off >>= 1) p += __shfl_xor(p, off);
        if (lane == 0) {
            ull pk = ((ull)fkey(p) << 32) | (unsigned)c;
            best = pk < best ? pk : best;
        }
    }
    if (lane == 0) atomicMin(&packed_fix[b], best);
}
__global__ void k_decode_force(const ull* __restrict__ packed_fix, float2* __restrict__ xy) {
    int i = blockIdx.x * 256 + threadIdx.x;
    if (i < B_) {
        int c = (int)(unsigned)(packed_fix[i] & 0xffffffffull);
        xy[i] = make_float2((float)(c / W_), (float)(c % W_));
    }
}
__global__ __launch_bounds__(256) void k_update_fallback(const float* __restrict__ x, const float* __restrict__ w0,
                                                         const float2* __restrict__ xy, const int* ep, const int* tp,
                                                         float* __restrict__ out) {
    int c = blockIdx.x;
    int d = threadIdx.x;
    float cyf = (float)(c / W_), cxf = (float)(c % W_);
    float lr, inv2r2;
    decay_params(ep, tp, lr, inv2r2);
    float acc = w0[(size_t)c * D_ + d];
    for (int i = 0; i < B_; ++i) {
        float2 p = xy[i];
        float dy = p.x - cyf, dx = p.y - cxf;
        float a = lr * __expf(-(dy * dy + dx * dx) * inv2r2);
        acc = fmaf(a, x[(size_t)i * D_ + d] - acc, acc);
    }
    out[(size_t)c * D_ + d] = acc;
}

extern "C" void kernel_launch(void* const* d_in, const int* in_sizes, int n_in,
                              void* d_out, int out_size, void* d_ws, size_t ws_size,
                              hipStream_t stream) {
    const float* x = (const float*)d_in[0];
    const float* w = (const float*)d_in[1];
    const int* ep = (const int*)d_in[2];
    const int* tp = (const int*)d_in[3];
    float* out = (float*)d_out;

    char* ws = (char*)d_ws;
    ull* pk1        = (ull*)ws;                      // 8KB    @ 0
    int2* bxy       = (int2*)(ws + 16384);           // 8KB    @ 16K
    float2* xyf     = (float2*)(ws + 16384);         // (fallback alias)
    float* T        = (float*)(ws + 24576);          // 40KB   @ 24K
    float* wnorm    = (float*)(ws + 65536);          // 40.5KB @ 64K (incl +128 pad)
    ushort_t* xhT   = (ushort_t*)(ws + 131072);      // 512KB  @ 128K
    __half* xh      = (__half*)(ws + 655360);        // 512KB
    __half* wh      = (__half*)(ws + 1179648);       // 5.12MB
    ushort_t* coefT = (ushort_t*)(ws + 6553600);     // 20.48MB
    __half* h       = (__half*)(ws + 27262976);      // 20.97MB
    size_t required = 27262976 + (size_t)B_ * LD * 2;  // ~48.2MB

    if (ws_size >= required) {
        k_prep<<<NC / 4 + 64 + 1, 256, 0, stream>>>(w, x, wh, wnorm, xh, xhT, pk1);
        k_scores_mfma<<<dim3(8, NTC), 512, 0, stream>>>(wh, xh, wnorm, h, pk1);
        k_fix<<<B_, 256, 0, stream>>>(h, wnorm, x, w, pk1, bxy);
        k_scan<<<(NC * 8 + 255) / 256, 256, 0, stream>>>(bxy, ep, tp, coefT, T);
        k_update<<<dim3(4, 313), 256, 0, stream>>>(coefT, xhT, T, w, out);
    } else {
        k_initfix<<<4, 256, 0, stream>>>(pk1);
        k_exact_bmu<<<B_, 256, 0, stream>>>(x, w, pk1);
        k_decode_force<<<4, 256, 0, stream>>>(pk1, xyf);
        k_update_fallback<<<NC, 256, 0, stream>>>(x, w, xyf, ep, tp, out);
    }
}